// Round 1
// baseline (1158.327 us; speedup 1.0000x reference)
//
#include <hip/hip_runtime.h>

#define N_USER 100000
#define N_ITEM 100000
#define N_NODES 200000
#define NNZ 6400000
#define EMB 64
#define BATCH 1024

// ---------------------------------------------------------------------------
// Workspace layout (f32 unless noted):
//   ego     : N_NODES*EMB floats (51.2 MB)  current layer embeddings
//   side    : N_NODES*EMB floats (51.2 MB)  spmm output
//   row_ptr : N_NODES+1 ints     (0.8 MB)   CSR row starts (adj_row is sorted)
// ---------------------------------------------------------------------------

__device__ __forceinline__ float readlane_f(float v, int lane) {
    return __builtin_bit_cast(float,
        __builtin_amdgcn_readlane(__builtin_bit_cast(int, v), lane));
}

// row_ptr[r] = lower_bound(adj_row, r); every r in [0, N_NODES] written once.
__global__ void build_row_ptr(const int* __restrict__ row, int* __restrict__ row_ptr) {
    int i = blockIdx.x * blockDim.x + threadIdx.x;
    if (i >= NNZ) return;
    int b = row[i];
    int a = (i == 0) ? -1 : row[i - 1];
    for (int r = a + 1; r <= b; ++r) row_ptr[r] = i;
    if (i == NNZ - 1) {
        for (int r = b + 1; r <= N_NODES; ++r) row_ptr[r] = NNZ;
    }
}

// ego = [user_emb ; item_emb], float4 copy
__global__ void concat_ego(const float* __restrict__ ue, const float* __restrict__ ie,
                           float* __restrict__ ego) {
    int i = blockIdx.x * blockDim.x + threadIdx.x;   // float4 index
    const int nu4 = N_USER * EMB / 4;
    const int ni4 = N_ITEM * EMB / 4;
    if (i < nu4)            ((float4*)ego)[i] = ((const float4*)ue)[i];
    else if (i < nu4 + ni4) ((float4*)ego)[i] = ((const float4*)ie)[i - nu4];
}

__device__ __forceinline__ int batch_node(const int* users, const int* pos,
                                          const int* neg, int b) {
    int t = b >> 10, idx = b & 1023;
    if (t == 0) return users[idx];
    if (t == 1) return N_USER + pos[idx];
    return N_USER + neg[idx];
}

// layer-0 columns of the output: raw concatenated embeddings, gathered
__global__ void gather_layer0(const int* __restrict__ users, const int* __restrict__ pos,
                              const int* __restrict__ neg, const float* __restrict__ ego,
                              float* __restrict__ out) {
    int b = blockIdx.x;                 // 0..3071
    int node = batch_node(users, pos, neg, b);
    out[(size_t)b * 256 + threadIdx.x] = ego[(size_t)node * EMB + threadIdx.x];
}

// CSR SpMM: one wave per row, lane = embedding dim. col/val are wave-uniform
// loads (scalarized); x-gather is a fully coalesced 256B row read per nnz.
__global__ __launch_bounds__(256) void spmm_csr(
        const int* __restrict__ row_ptr, const int* __restrict__ col,
        const float* __restrict__ val, const float* __restrict__ x,
        float* __restrict__ y) {
    int wave = (blockIdx.x * blockDim.x + threadIdx.x) >> 6;
    int lane = threadIdx.x & 63;
    if (wave >= N_NODES) return;
    int j0 = row_ptr[wave], j1 = row_ptr[wave + 1];
    float acc = 0.f;
    int j = j0;
    // unroll-by-4 with batched index/val fetch so the x-gathers pipeline
    for (; j + 4 <= j1; j += 4) {
        int   c0 = col[j], c1 = col[j + 1], c2 = col[j + 2], c3 = col[j + 3];
        float v0 = val[j], v1 = val[j + 1], v2 = val[j + 2], v3 = val[j + 3];
        float x0 = x[(size_t)c0 * EMB + lane];
        float x1 = x[(size_t)c1 * EMB + lane];
        float x2 = x[(size_t)c2 * EMB + lane];
        float x3 = x[(size_t)c3 * EMB + lane];
        acc += v0 * x0 + v1 * x1 + v2 * x2 + v3 * x3;
    }
    for (; j < j1; ++j) acc += val[j] * x[(size_t)col[j] * EMB + lane];
    y[(size_t)wave * EMB + lane] = acc;
}

// ego <- leaky_relu(side@Wgc + bgc + (ego*side)@Wbi + bbi), in place.
// One wave per row (grid-stride). Each lane holds one output column of both
// weight matrices in VGPRs (128 regs); row values broadcast via v_readlane.
__global__ __launch_bounds__(256) void dense_layer(
        float* __restrict__ ego, const float* __restrict__ side,
        const float* __restrict__ Wgc, const float* __restrict__ bgc,
        const float* __restrict__ Wbi, const float* __restrict__ bbi) {
    int lane = threadIdx.x & 63;
    float wgc[EMB], wbi[EMB];
#pragma unroll
    for (int k = 0; k < EMB; ++k) {
        wgc[k] = Wgc[k * EMB + lane];    // column `lane`
        wbi[k] = Wbi[k * EMB + lane];
    }
    float bg = bgc[lane], bb = bbi[lane];

    int wave   = (blockIdx.x * blockDim.x + threadIdx.x) >> 6;
    int nwaves = (gridDim.x * blockDim.x) >> 6;
    for (int r = wave; r < N_NODES; r += nwaves) {
        float sv = side[(size_t)r * EMB + lane];
        float ev = ego[(size_t)r * EMB + lane];
        float pv = ev * sv;
        float a1 = bg, a2 = bb;
#pragma unroll
        for (int k = 0; k < EMB; ++k) {
            a1 += readlane_f(sv, k) * wgc[k];
            a2 += readlane_f(pv, k) * wbi[k];
        }
        float c = a1 + a2;
        float o = c > 0.f ? c : 0.2f * c;
        ego[(size_t)r * EMB + lane] = o;   // row fully read before write: safe
    }
}

// gather batch rows of ego, L2-normalize, write to out columns [64*layer, ...)
__global__ void gather_norm(const int* __restrict__ users, const int* __restrict__ pos,
                            const int* __restrict__ neg, const float* __restrict__ ego,
                            float* __restrict__ out, int layer) {
    int b = blockIdx.x;                 // 0..3071
    int lane = threadIdx.x;             // 0..63
    int node = batch_node(users, pos, neg, b);
    float v = ego[(size_t)node * EMB + lane];
    float s = v * v;
#pragma unroll
    for (int off = 32; off > 0; off >>= 1) s += __shfl_xor(s, off);
    float n = fmaxf(sqrtf(s), 1e-12f);
    out[(size_t)b * 256 + layer * EMB + lane] = v / n;
}

extern "C" void kernel_launch(void* const* d_in, const int* in_sizes, int n_in,
                              void* d_out, int out_size, void* d_ws, size_t ws_size,
                              hipStream_t stream) {
    const int*   users    = (const int*)d_in[0];
    const int*   pos      = (const int*)d_in[1];
    const int*   neg      = (const int*)d_in[2];
    const int*   adj_row  = (const int*)d_in[3];
    const int*   adj_col  = (const int*)d_in[4];
    const float* adj_val  = (const float*)d_in[5];
    const float* user_emb = (const float*)d_in[6];
    const float* item_emb = (const float*)d_in[7];
    // d_in[8..19]: W_gc_0, b_gc_0, W_bi_0, b_bi_0, W_gc_1, ... (4 per layer)

    float* ego     = (float*)d_ws;
    float* side    = ego + (size_t)N_NODES * EMB;
    int*   row_ptr = (int*)(side + (size_t)N_NODES * EMB);
    float* out     = (float*)d_out;

    build_row_ptr<<<(NNZ + 255) / 256, 256, 0, stream>>>(adj_row, row_ptr);
    concat_ego<<<(N_NODES * EMB / 4 + 255) / 256, 256, 0, stream>>>(user_emb, item_emb, ego);
    gather_layer0<<<3 * BATCH, 64, 0, stream>>>(users, pos, neg, ego, out);

    for (int k = 0; k < 3; ++k) {
        const float* Wgc = (const float*)d_in[8 + 4 * k];
        const float* bgc = (const float*)d_in[9 + 4 * k];
        const float* Wbi = (const float*)d_in[10 + 4 * k];
        const float* bbi = (const float*)d_in[11 + 4 * k];
        spmm_csr<<<N_NODES / 4, 256, 0, stream>>>(row_ptr, adj_col, adj_val, ego, side);
        dense_layer<<<2048, 256, 0, stream>>>(ego, side, Wgc, bgc, Wbi, bbi);
        gather_norm<<<3 * BATCH, 64, 0, stream>>>(users, pos, neg, ego, out, k + 1);
    }
}